// Round 1
// baseline (522.727 us; speedup 1.0000x reference)
//
#include <hip/hip_runtime.h>

#define BATCH 8
#define NPTS  2048
#define C     64
#define TA    16     // a-points per block
#define TB    32     // b-points per LDS tile
#define THREADS 256

// LDS budget: union(in: 32*64*4 + 32*4*4 = 8.5KB, s: 16*3*64*4 = 12KB) = 12KB
//           + wkT: 3*64*64*4 = 48KB  -> 60KB total, 2 blocks/CU.
__global__ __launch_bounds__(THREADS, 2)
void nconv_kernel(const float* __restrict__ feat,   // [z][n][C]
                  const float* __restrict__ geom,   // [z][n][3]
                  const float* __restrict__ Wk,     // [x][i][j]
                  float* __restrict__ out) {        // [z][n][C]
  __shared__ __align__(16) union {
    struct { float f[TB][C]; float g[TB][4]; } in;
    float s[TA][3][C];
  } u;
  __shared__ __align__(16) float wkT[3][C][C];  // [x][j][i] (transposed for epilogue)

  const int tid = threadIdx.x;
  const int z  = blockIdx.y;
  const int a0 = blockIdx.x * TA;

  // Stage Wk transposed: [x][i][j] -> [x][j][i]. Once per block; write conflicts
  // are a one-time ~500cyc cost, buys conflict-free epilogue reads.
  for (int k = tid; k < 3 * C * C; k += THREADS) {
    const int x = k >> 12;
    const int i = (k >> 6) & (C - 1);
    const int j = k & (C - 1);
    wkT[x][j][i] = Wk[k];
  }

  const int a_local = tid >> 4;        // 0..15
  const int j0      = (tid & 15) << 2; // 0,4,...,60
  const int a       = a0 + a_local;

  const float* __restrict__ featz = feat + (size_t)z * NPTS * C;
  const float* __restrict__ geomz = geom + (size_t)z * NPTS * 3;

  const float ga0 = geomz[a * 3 + 0];
  const float ga1 = geomz[a * 3 + 1];
  const float ga2 = geomz[a * 3 + 2];

  float s[3][4];
#pragma unroll
  for (int x = 0; x < 3; ++x)
#pragma unroll
    for (int jj = 0; jj < 4; ++jj) s[x][jj] = 0.f;

  for (int b0 = 0; b0 < NPTS; b0 += TB) {
    __syncthreads();
    // stage features [TB][C] as float4, perfectly coalesced
#pragma unroll
    for (int k = 0; k < (TB * C) / (4 * THREADS); ++k) {
      const int fi  = tid + k * THREADS;   // float4 index
      const int row = fi >> 4;             // C/4 = 16 float4 per row
      const int c4  = (fi & 15) << 2;
      *(float4*)&u.in.f[row][c4] = *(const float4*)&featz[(b0 + row) * C + c4];
    }
    if (tid < TB * 3) {
      u.in.g[tid / 3][tid % 3] = geomz[(b0 + tid / 3) * 3 + tid % 3];
    }
    __syncthreads();

#pragma unroll 4
    for (int bb = 0; bb < TB; ++bb) {
      const float d0 = u.in.g[bb][0] - ga0;
      const float d1 = u.in.g[bb][1] - ga1;
      const float d2 = u.in.g[bb][2] - ga2;
      const float n2 = d0 * d0 + d1 * d1 + d2 * d2;
      // norm < 1  <=>  norm^2 < 1 (sqrt monotone, correctly rounded)
      if (n2 < 1.0f) {
        const float4 f = *(const float4*)&u.in.f[bb][j0];
        s[0][0] += d0 * f.x; s[0][1] += d0 * f.y; s[0][2] += d0 * f.z; s[0][3] += d0 * f.w;
        s[1][0] += d1 * f.x; s[1][1] += d1 * f.y; s[1][2] += d1 * f.z; s[1][3] += d1 * f.w;
        s[2][0] += d2 * f.x; s[2][1] += d2 * f.y; s[2][2] += d2 * f.z; s[2][3] += d2 * f.w;
      }
    }
  }

  __syncthreads();  // everyone done reading u.in before overwriting with u.s
#pragma unroll
  for (int x = 0; x < 3; ++x)
    *(float4*)&u.s[a_local][x][j0] = make_float4(s[x][0], s[x][1], s[x][2], s[x][3]);
  __syncthreads();

  // Epilogue: thread -> (a2 = tid>>4, i0 = (tid&15)*4)
  // out[a,i] = sum_{x,j} s[a,x,j] * Wk[x,i,j]   (N_NORM=1 -> no scale)
  const int a2 = tid >> 4;
  const int i0 = (tid & 15) << 2;
  float acc0 = 0.f, acc1 = 0.f, acc2 = 0.f, acc3 = 0.f;
#pragma unroll
  for (int x = 0; x < 3; ++x) {
#pragma unroll 8
    for (int j = 0; j < C; ++j) {
      const float  sv = u.s[a2][x][j];              // broadcast across 16 lanes
      const float4 w  = *(const float4*)&wkT[x][j][i0];  // contiguous over lanes
      acc0 += sv * w.x; acc1 += sv * w.y; acc2 += sv * w.z; acc3 += sv * w.w;
    }
  }
  *(float4*)&out[((size_t)z * NPTS + a0 + a2) * C + i0] =
      make_float4(acc0, acc1, acc2, acc3);
}

extern "C" void kernel_launch(void* const* d_in, const int* in_sizes, int n_in,
                              void* d_out, int out_size, void* d_ws, size_t ws_size,
                              hipStream_t stream) {
  const float* feat = (const float*)d_in[0];  // [8,2048,64]
  const float* geom = (const float*)d_in[1];  // [8,2048,3]
  const float* Wk   = (const float*)d_in[2];  // [3,64,64]
  float* out = (float*)d_out;                 // [8,2048,64]

  dim3 grid(NPTS / TA, BATCH);  // (128, 8) = 1024 blocks
  nconv_kernel<<<grid, THREADS, 0, stream>>>(feat, geom, Wk, out);
}

// Round 2
// 144.128 us; speedup vs baseline: 3.6268x; 3.6268x over previous
//
#include <hip/hip_runtime.h>
#include <stdint.h>

#define NPTS 2048
#define NZ   8

typedef __attribute__((ext_vector_type(8))) short bf16x8;
typedef __attribute__((ext_vector_type(4))) float f32x4;
typedef __attribute__((ext_vector_type(4))) unsigned int u32x4;

// ---- workspace layout (bytes) ----
// Bp: pre-tiled B' for the mask-GEMM: [z][chunk=64][q=256][k=32] bf16,
//     16B sub-chunks XOR-swizzled by (q&3) for LDS bank spread.
#define BP_OFF    0ULL
#define BP_BYTES  (8ULL * 64 * 256 * 64)           // 8,388,608
#define CG_OFF    (BP_OFF + BP_BYTES)
#define CG_BYTES  (16384ULL * 256 * 2)             // 8,388,608 (C = M@Bp, bf16)
#define W2_OFF    (CG_OFF + CG_BYTES)
#define W2_ROW    208                              // 192 real + 16 pad (16B rows)
#define W2_BYTES  (64ULL * W2_ROW * 2)             // 26,624
#define WX2_OFF   (W2_OFF + W2_BYTES)
#define WX2_ROW   72                               // 64 real + 8 pad
#define WX2_BYTES (192ULL * WX2_ROW * 2)           // 27,648
#define WKLDS_BYTES (W2_BYTES + WX2_BYTES)         // 54,272 = 53*1024

__device__ __forceinline__ unsigned short f2bf(float f) {
  union { float f; unsigned u; } v; v.f = f;
  unsigned r = (v.u + 0x7FFFu + ((v.u >> 16) & 1u)) >> 16;  // RNE
  return (unsigned short)r;
}

__device__ __forceinline__ void async_copy16(const void* g, void* l) {
  __builtin_amdgcn_global_load_lds(
      (const __attribute__((address_space(1))) unsigned int*)g,
      (__attribute__((address_space(3))) unsigned int*)l, 16, 0, 0);
}

// ================= K1: prep Bp (tiled+swizzled bf16) and W2/Wx2 =================
__global__ __launch_bounds__(256) void k1_prep(const float* __restrict__ feat,
                                               const float* __restrict__ geom,
                                               const float* __restrict__ Wk,
                                               unsigned char* __restrict__ ws) {
  const int blk = blockIdx.x;
  const int t = threadIdx.x;
  __shared__ __align__(16) float Flds[32][68];  // pad 68: 16B-aligned rows
  __shared__ float glds[96];

  if (blk < 512) {
    const int z = blk >> 6, ch = blk & 63;
    const int b0 = ch * 32;
    const float* fz = feat + ((size_t)z * NPTS + b0) * 64;
    const float* gz = geom + ((size_t)z * NPTS + b0) * 3;
    {  // stage F tile [32][64] coalesced
      const int row = t >> 3, j0 = (t & 7) << 3;
      float4 v0 = *(const float4*)&fz[row * 64 + j0];
      float4 v1 = *(const float4*)&fz[row * 64 + j0 + 4];
      *(float4*)&Flds[row][j0] = v0;
      *(float4*)&Flds[row][j0 + 4] = v1;
    }
    if (t < 96) glds[t] = gz[t];
    __syncthreads();
    // thread t owns output row q: Bp[z][ch][q][k=0..31], swizzled 16B chunks
    const int q = t, x = q >> 6, j = q & 63, sw = q & 3;
    unsigned char* bp = ws + BP_OFF + (((size_t)z * 64 + ch) * 256 + q) * 64;
#pragma unroll
    for (int c = 0; c < 4; ++c) {
      u32x4 pv;
#pragma unroll
      for (int p = 0; p < 4; ++p) {
        const int k0 = c * 8 + p * 2;
        float f0 = Flds[k0][j], f1 = Flds[k0 + 1][j];
        if (x < 3) { f0 *= glds[k0 * 3 + x]; f1 *= glds[(k0 + 1) * 3 + x]; }
        pv[p] = (unsigned)f2bf(f0) | ((unsigned)f2bf(f1) << 16);
      }
      *(u32x4*)(bp + ((c ^ sw) << 4)) = pv;
    }
  } else if (blk == 512) {
    // W2[i][q] = Wk[x][i][j], q = x*64+j  (rows padded to 208)
    unsigned short* w2 = (unsigned short*)(ws + W2_OFF);
    for (int e = t; e < 64 * 192; e += 256) {
      const int i = e / 192, q = e % 192;
      const int x = q >> 6, j = q & 63;
      w2[i * W2_ROW + q] = f2bf(Wk[x * 4096 + i * 64 + j]);
    }
  } else {
    // Wx2[xi][j] = Wk[x][i][j], xi = x*64+i (rows padded to 72)
    unsigned short* wx = (unsigned short*)(ws + WX2_OFF);
    for (int e = t; e < 192 * 64; e += 256) {
      const int xi = e >> 6, j = e & 63;
      wx[xi * WX2_ROW + j] = f2bf(Wk[(xi >> 6) * 4096 + (xi & 63) * 64 + j]);
    }
  }
}

// ================= K2: mask-fused GEMM  C[64a x 256q] = M @ Bp =================
// block: one z, 64-row a-tile. 4 waves: wave w -> rows 32*(w>>1)+[0,32), cols 128*(w&1)+[0,128)
__global__ __launch_bounds__(256) void k2_gemm(const float* __restrict__ geom,
                                               unsigned char* __restrict__ ws) {
  __shared__ __align__(16) unsigned char Btile[16384];  // [q=256][k=32] bf16 (swizzled)
  __shared__ __align__(16) unsigned char Am[4096];      // [m=64][k=32] bf16 mask (swizzled)
  __shared__ __align__(16) float glds[NPTS * 3];        // full geometry of this z

  const int t = threadIdx.x, lane = t & 63, w = t >> 6;
  const int quad = lane >> 4, n = lane & 15;
  const int z = blockIdx.x >> 5;
  const int a0 = (blockIdx.x & 31) * 64;
  const float* gz = geom + (size_t)z * NPTS * 3;

#pragma unroll
  for (int i = 0; i < 6; ++i) {  // 6144 floats coalesced
    const int idx = (i * 256 + t) * 4;
    *(float4*)&glds[idx] = *(const float4*)&gz[idx];
  }
  __syncthreads();

  // producer: wave w generates mask rows m = 16w + n
  const int mrow = 16 * w + n;
  const float ga0 = glds[(a0 + mrow) * 3 + 0];
  const float ga1 = glds[(a0 + mrow) * 3 + 1];
  const float ga2 = glds[(a0 + mrow) * 3 + 2];

  f32x4 acc[2][8];
#pragma unroll
  for (int rb = 0; rb < 2; ++rb)
#pragma unroll
    for (int cb = 0; cb < 8; ++cb)
#pragma unroll
      for (int r = 0; r < 4; ++r) acc[rb][cb][r] = 0.f;

  const unsigned char* bpz = ws + BP_OFF + (size_t)z * 64 * 16384;
  const int swz = (quad ^ (n & 3)) << 4;   // 16B-chunk swizzle offset
  const int rbase = (w >> 1) * 2;

  for (int step = 0; step < 64; ++step) {
    __syncthreads();  // prev frag reads done before overwrite
    {  // stage Bp tile: 16KB via global_load_lds, 4 issues/wave
      const unsigned char* src = bpz + (size_t)step * 16384;
#pragma unroll
      for (int it = 0; it < 4; ++it) {
        const int off = (w * 4 + it) * 1024;
        async_copy16(src + off + lane * 16, Btile + off);
      }
    }
    {  // masks: lane computes A[m=16w+n][k=quad*8 .. +7]
      const int gb = (step * 32 + quad * 8) * 3;  // 16B-aligned (24 floats)
      float gf[24];
#pragma unroll
      for (int i = 0; i < 6; ++i) *(float4*)&gf[i * 4] = *(const float4*)&glds[gb + i * 4];
      u32x4 pv;
#pragma unroll
      for (int p = 0; p < 4; ++p) {
        const float d0 = gf[(2 * p) * 3 + 0] - ga0;
        const float d1 = gf[(2 * p) * 3 + 1] - ga1;
        const float d2 = gf[(2 * p) * 3 + 2] - ga2;
        const float e0 = gf[(2 * p + 1) * 3 + 0] - ga0;
        const float e1 = gf[(2 * p + 1) * 3 + 1] - ga1;
        const float e2 = gf[(2 * p + 1) * 3 + 2] - ga2;
        const float n2a = fmaf(d0, d0, fmaf(d1, d1, d2 * d2));
        const float n2b = fmaf(e0, e0, fmaf(e1, e1, e2 * e2));
        const unsigned lo = (n2a < 1.0f) ? 0x3F80u : 0u;
        const unsigned hi = (n2b < 1.0f) ? 0x3F800000u : 0u;
        pv[p] = lo | hi;
      }
      *(u32x4*)(Am + mrow * 64 + swz) = pv;
    }
    __syncthreads();  // drains vmcnt (staging) + lgkmcnt (mask writes)

    bf16x8 Af[2];
#pragma unroll
    for (int rb = 0; rb < 2; ++rb) {
      const int row = (rbase + rb) * 16 + n;
      Af[rb] = *(const bf16x8*)(Am + row * 64 + swz);
    }
#pragma unroll
    for (int cb = 0; cb < 8; ++cb) {
      const int qrow = ((w & 1) * 8 + cb) * 16 + n;
      const bf16x8 Bf = *(const bf16x8*)(Btile + qrow * 64 + swz);
      acc[0][cb] = __builtin_amdgcn_mfma_f32_16x16x32_bf16(Af[0], Bf, acc[0][cb], 0, 0, 0);
      acc[1][cb] = __builtin_amdgcn_mfma_f32_16x16x32_bf16(Af[1], Bf, acc[1][cb], 0, 0, 0);
    }
  }

  // epilogue: C -> bf16 to Cg.  C/D: col = n (lane&15), row = quad*4 + r
  unsigned short* cg = (unsigned short*)(ws + CG_OFF);
#pragma unroll
  for (int rb = 0; rb < 2; ++rb)
#pragma unroll
    for (int cb = 0; cb < 8; ++cb)
#pragma unroll
      for (int r = 0; r < 4; ++r) {
        const int m = (w >> 1) * 32 + rb * 16 + quad * 4 + r;
        const int q = (w & 1) * 128 + cb * 16 + n;
        cg[((size_t)z * NPTS + a0 + m) * 256 + q] = f2bf(acc[rb][cb][r]);
      }
}

// ================= K3: out = C[:, :192] @ W2  -  (ga . V),  V = T0 @ Wx2 ========
__global__ __launch_bounds__(256) void k3_out(const float* __restrict__ geom,
                                              const unsigned char* __restrict__ ws,
                                              float* __restrict__ out) {
  __shared__ __align__(16) unsigned char wk_lds[WKLDS_BYTES];
  const int t = threadIdx.x, lane = t & 63, w = t >> 6;
  const int quad = lane >> 4, n = lane & 15;

  const unsigned char* wsrc = ws + W2_OFF;  // W2 then Wx2, contiguous 53 KiB
  for (int c = w; c < 53; c += 4) async_copy16(wsrc + c * 1024 + lane * 16, wk_lds + c * 1024);
  __syncthreads();
  const unsigned char* W2l = wk_lds;             // [64 i][208 q] bf16
  const unsigned char* Wxl = wk_lds + W2_BYTES;  // [192 xi][72 j] bf16

  const size_t R0 = (size_t)blockIdx.x * 64;
  const size_t row = R0 + 16 * w + n;  // A-frag row m = n
  const unsigned char* cgrow = ws + CG_OFF + row * 512;

  bf16x8 Amain[6], At0[2];
#pragma unroll
  for (int kb = 0; kb < 6; ++kb) Amain[kb] = *(const bf16x8*)(cgrow + kb * 64 + quad * 16);
#pragma unroll
  for (int kb = 0; kb < 2; ++kb) At0[kb] = *(const bf16x8*)(cgrow + 384 + kb * 64 + quad * 16);

  f32x4 mn[4], V[12];
#pragma unroll
  for (int i = 0; i < 4; ++i)
#pragma unroll
    for (int r = 0; r < 4; ++r) mn[i][r] = 0.f;
#pragma unroll
  for (int i = 0; i < 12; ++i)
#pragma unroll
    for (int r = 0; r < 4; ++r) V[i][r] = 0.f;

#pragma unroll
  for (int kb = 0; kb < 6; ++kb)
#pragma unroll
    for (int cb = 0; cb < 4; ++cb) {
      const bf16x8 Bf = *(const bf16x8*)(W2l + (cb * 16 + n) * (W2_ROW * 2) + kb * 64 + quad * 16);
      mn[cb] = __builtin_amdgcn_mfma_f32_16x16x32_bf16(Amain[kb], Bf, mn[cb], 0, 0, 0);
    }
#pragma unroll
  for (int kb = 0; kb < 2; ++kb)
#pragma unroll
    for (int cb = 0; cb < 12; ++cb) {
      const bf16x8 Bf = *(const bf16x8*)(Wxl + (cb * 16 + n) * (WX2_ROW * 2) + kb * 64 + quad * 16);
      V[cb] = __builtin_amdgcn_mfma_f32_16x16x32_bf16(At0[kb], Bf, V[cb], 0, 0, 0);
    }

#pragma unroll
  for (int r = 0; r < 4; ++r) {
    const size_t af = R0 + 16 * w + quad * 4 + r;  // output row (C/D row = quad*4+r)
    const float g0 = geom[af * 3 + 0], g1 = geom[af * 3 + 1], g2 = geom[af * 3 + 2];
#pragma unroll
    for (int cb = 0; cb < 4; ++cb) {
      const float v = mn[cb][r] - g0 * V[cb][r] - g1 * V[cb + 4][r] - g2 * V[cb + 8][r];
      out[af * 64 + cb * 16 + n] = v;
    }
  }
}

extern "C" void kernel_launch(void* const* d_in, const int* in_sizes, int n_in,
                              void* d_out, int out_size, void* d_ws, size_t ws_size,
                              hipStream_t stream) {
  const float* feat = (const float*)d_in[0];  // [8,2048,64]
  const float* geom = (const float*)d_in[1];  // [8,2048,3]
  const float* Wk   = (const float*)d_in[2];  // [3,64,64]
  float* out = (float*)d_out;                 // [8,2048,64] fp32
  unsigned char* ws = (unsigned char*)d_ws;   // needs ~16.1 MB

  k1_prep<<<dim3(514), 256, 0, stream>>>(feat, geom, Wk, ws);
  k2_gemm<<<dim3(256), 256, 0, stream>>>(geom, ws);
  k3_out<<<dim3(256), 256, 0, stream>>>(geom, ws, out);
}

// Round 4
// 109.791 us; speedup vs baseline: 4.7611x; 1.3128x over previous
//
#include <hip/hip_runtime.h>
#include <stdint.h>

#define NPTS 2048

// ---- workspace layout (bytes) ----
// Bp fragment-ordered: [z][qb=16][s=64][frag 1KB]; frag = 16 q-cols x 32 k,
// lane (quad,n) entry at n*64 + quad*16 (bf16 pairs along k).
#define BP_OFF    0ULL
#define BP_BYTES  (8ULL * 16 * 64 * 1024)      // 8 MB
#define W2F_OFF   (BP_OFF + BP_BYTES)
#define W2F_BYTES (24ULL * 1024)               // 24 frags (kb0..5 x cb0..3)
#define WXF_OFF   (W2F_OFF + W2F_BYTES)
#define WXF_BYTES (24ULL * 1024)               // 24 frags (kb0..1 x cb0..11)

typedef __attribute__((ext_vector_type(8))) short bf16x8;
typedef __attribute__((ext_vector_type(4))) float f32x4;
typedef __attribute__((ext_vector_type(4))) unsigned int u32x4;

__device__ __forceinline__ unsigned f2bf(float f) {
  union { float f; unsigned u; } v; v.f = f;
  return (v.u + 0x7FFFu + ((v.u >> 16) & 1u)) >> 16;  // RNE
}

__device__ __forceinline__ bf16x8 pack8(const float4 a, const float4 b) {
  u32x4 r;
  r[0] = f2bf(a.x) | (f2bf(a.y) << 16);
  r[1] = f2bf(a.z) | (f2bf(a.w) << 16);
  r[2] = f2bf(b.x) | (f2bf(b.y) << 16);
  r[3] = f2bf(b.z) | (f2bf(b.w) << 16);
  union { u32x4 u; bf16x8 h; } c; c.u = r; return c.h;
}

// ================= K1: fragment-ordered Bp + weight fragments =================
// (verbatim from R3 — produced correct data; plain stores, single barrier)
__global__ __launch_bounds__(256) void k1_prep(const float* __restrict__ feat,
                                               const float* __restrict__ geom,
                                               const float* __restrict__ Wk,
                                               unsigned char* __restrict__ ws) {
  const int blk = blockIdx.x, t = threadIdx.x;
  if (blk < 512) {
    const int z = blk >> 6, s = blk & 63;        // 32 b-points per s-chunk
    __shared__ __align__(16) float F[32][68];    // pad 68 keeps rows 16B-aligned
    __shared__ float g[96];
    const float* fz = feat + ((size_t)z * NPTS + s * 32) * 64;
    {
      const int row = t >> 3, j0 = (t & 7) << 3;
      *(float4*)&F[row][j0]     = *(const float4*)&fz[row * 64 + j0];
      *(float4*)&F[row][j0 + 4] = *(const float4*)&fz[row * 64 + j0 + 4];
    }
    if (t < 96) g[t] = geom[((size_t)z * NPTS + s * 32) * 3 + t];
    __syncthreads();
    // thread t owns q-col t: Bp[q][k] = F[k][j] * (x<3 ? g[k][x] : 1), q=x*64+j
    const int q = t, x = q >> 6, j = q & 63, qb = q >> 4, nn = q & 15;
    unsigned char* dst = ws + BP_OFF + (((size_t)z * 16 + qb) * 64 + s) * 1024 + nn * 64;
#pragma unroll
    for (int quad = 0; quad < 4; ++quad) {
      u32x4 pv;
#pragma unroll
      for (int p = 0; p < 4; ++p) {
        const int k0 = quad * 8 + 2 * p;
        float f0 = F[k0][j], f1 = F[k0 + 1][j];
        if (x < 3) { f0 *= g[k0 * 3 + x]; f1 *= g[(k0 + 1) * 3 + x]; }
        pv[p] = f2bf(f0) | (f2bf(f1) << 16);
      }
      *(u32x4*)(dst + quad * 16) = pv;
    }
  } else if (blk == 512) {
    // W2F frag (kb,cb): lane (quad,n) holds W2[k=kb*32+quad*8+jj][i=cb*16+n]
    for (int e = t; e < 1536; e += 256) {
      const int frag = e >> 6, lp = e & 63, nn = lp >> 2, qd = lp & 3;
      const int kb = frag >> 2, cb = frag & 3;
      u32x4 pv;
#pragma unroll
      for (int p = 0; p < 4; ++p) {
        const int k0 = kb * 32 + qd * 8 + 2 * p;
        const float v0 = Wk[(k0 >> 6) * 4096 + (cb * 16 + nn) * 64 + (k0 & 63)];
        const float v1 = Wk[((k0 + 1) >> 6) * 4096 + (cb * 16 + nn) * 64 + ((k0 + 1) & 63)];
        pv[p] = f2bf(v0) | (f2bf(v1) << 16);
      }
      *(u32x4*)(ws + W2F_OFF + (size_t)frag * 1024 + lp * 16) = pv;
    }
  } else {
    // WXF frag (kb,cb): lane holds Wk[xi>>6][xi&63][k=kb*32+quad*8+jj], xi=cb*16+n
    for (int e = t; e < 1536; e += 256) {
      const int frag = e >> 6, lp = e & 63, nn = lp >> 2, qd = lp & 3;
      const int kb = frag / 12, cb = frag % 12, xi = cb * 16 + nn;
      u32x4 pv;
#pragma unroll
      for (int p = 0; p < 4; ++p) {
        const int k0 = kb * 32 + qd * 8 + 2 * p;
        const float v0 = Wk[(xi >> 6) * 4096 + (xi & 63) * 64 + k0];
        const float v1 = Wk[(xi >> 6) * 4096 + (xi & 63) * 64 + k0 + 1];
        pv[p] = f2bf(v0) | (f2bf(v1) << 16);
      }
      *(u32x4*)(ws + WXF_OFF + (size_t)frag * 1024 + lp * 16) = pv;
    }
  }
}

// ====== K2: bitmask precompute -> barrier-free mask-GEMM -> fused epilogue ======
// 256 blocks = (z, 64-row a-tile), 512 threads = 8 waves.
// Wave w: all 64 a-rows x q-cols 32w..32w+31 (qb frags 2w, 2w+1).
// K-loop has ZERO __syncthreads: masks are read-only LDS bits, B via reg prefetch.
__global__ __launch_bounds__(512, 2) void k2_fused(const float* __restrict__ geom,
                                                   const unsigned char* __restrict__ ws,
                                                   float* __restrict__ out) {
  __shared__ __align__(16) float glds[NPTS * 3];   // 24576 B
  __shared__ unsigned int Mw[64 * 64];             // 16384 B: Mw[s][row], bit k = mask(row, s*32+k)
  __shared__ __align__(16) float Ct[32 * 256];     // 32768 B (epilogue transpose)

  const int t = threadIdx.x, lane = t & 63, w = t >> 6;   // w = 0..7
  const int quad = lane >> 4, n = lane & 15;
  const int z = blockIdx.x >> 5, a0 = (blockIdx.x & 31) * 64;

  const float* gz = geom + (size_t)z * NPTS * 3;
#pragma unroll
  for (int i = 0; i < 3; ++i) {
    const int idx = (i * 512 + t) * 4;
    *(float4*)&glds[idx] = *(const float4*)&gz[idx];
  }
  __syncthreads();

  // ---- mask bit precompute: thread (row mr = t&63, s-range sg = t>>6) ----
  {
    const int mr = t & 63, sg = t >> 6;
    const float pa0 = glds[(a0 + mr) * 3 + 0];
    const float pa1 = glds[(a0 + mr) * 3 + 1];
    const float pa2 = glds[(a0 + mr) * 3 + 2];
#pragma unroll
    for (int si = 0; si < 8; ++si) {
      const int s = sg * 8 + si;
      unsigned bits = 0;
#pragma unroll
      for (int k8 = 0; k8 < 4; ++k8) {         // 8 b-points per group
        float v[24];
#pragma unroll
        for (int i = 0; i < 6; ++i)
          *(float4*)&v[i * 4] = *(const float4*)&glds[s * 96 + k8 * 24 + i * 4];
#pragma unroll
        for (int p = 0; p < 8; ++p) {
          const float d0 = v[p * 3 + 0] - pa0;
          const float d1 = v[p * 3 + 1] - pa1;
          const float d2 = v[p * 3 + 2] - pa2;
          const float n2 = fmaf(d2, d2, fmaf(d1, d1, d0 * d0));
          bits |= (n2 < 1.0f ? 1u : 0u) << (k8 * 8 + p);
        }
      }
      Mw[s * 64 + mr] = bits;
    }
  }
  __syncthreads();  // Mw is READ-ONLY from here on — no more barriers until epilogue

  // ---- barrier-free K-loop ----
  const unsigned char* bpz = ws + BP_OFF + (size_t)z * 16 * 65536;
  const int fragoff = n * 64 + quad * 16;
  const int qsh = quad * 8;

  f32x4 acc[4][2];
#pragma unroll
  for (int rb = 0; rb < 4; ++rb)
#pragma unroll
    for (int cb = 0; cb < 2; ++cb)
#pragma unroll
      for (int r = 0; r < 4; ++r) acc[rb][cb][r] = 0.f;

  bf16x8 B0[2], B1[2];
#pragma unroll
  for (int cb = 0; cb < 2; ++cb) {
    B0[cb] = *(const bf16x8*)(bpz + ((size_t)(2 * w + cb) * 64 + 0) * 1024 + fragoff);
    B1[cb] = *(const bf16x8*)(bpz + ((size_t)(2 * w + cb) * 64 + 1) * 1024 + fragoff);
  }

#define UNPACK_MFMA(SS, BB)                                                       \
  {                                                                               \
    unsigned mb[4];                                                               \
    _Pragma("unroll") for (int rb = 0; rb < 4; ++rb)                              \
        mb[rb] = Mw[(SS) * 64 + rb * 16 + n];                                     \
    _Pragma("unroll") for (int rb = 0; rb < 4; ++rb) {                            \
      const unsigned mq = mb[rb] >> qsh;                                          \
      u32x4 aw;                                                                   \
      _Pragma("unroll") for (int tt = 0; tt < 4; ++tt)                            \
          aw[tt] = ((mq >> (2 * tt)) & 1u) * 0x3F80u |                            \
                   ((mq >> (2 * tt + 1)) & 1u) * 0x3F800000u;                     \
      union { u32x4 u; bf16x8 h; } cv; cv.u = aw;                                 \
      _Pragma("unroll") for (int cb = 0; cb < 2; ++cb)                            \
        acc[rb][cb] = __builtin_amdgcn_mfma_f32_16x16x32_bf16(                    \
            cv.h, BB[cb], acc[rb][cb], 0, 0, 0);                                  \
    }                                                                             \
  }

  for (int s2 = 0; s2 < 64; s2 += 2) {
    UNPACK_MFMA(s2, B0)
    {
      const int sl = (s2 + 2) > 63 ? 63 : (s2 + 2);
#pragma unroll
      for (int cb = 0; cb < 2; ++cb)
        B0[cb] = *(const bf16x8*)(bpz + ((size_t)(2 * w + cb) * 64 + sl) * 1024 + fragoff);
    }
    UNPACK_MFMA(s2 + 1, B1)
    {
      const int sl = (s2 + 3) > 63 ? 63 : (s2 + 3);
#pragma unroll
      for (int cb = 0; cb < 2; ++cb)
        B1[cb] = *(const bf16x8*)(bpz + ((size_t)(2 * w + cb) * 64 + sl) * 1024 + fragoff);
    }
  }
#undef UNPACK_MFMA

  // ---- epilogue: acc -> Ct (two 32-row passes, XOR chunk swizzle) -> A-frags ----
  bf16x8 Across[8];
#pragma unroll
  for (int p = 0; p < 2; ++p) {
#pragma unroll
    for (int rb2 = 0; rb2 < 2; ++rb2)
#pragma unroll
      for (int cb = 0; cb < 2; ++cb)
#pragma unroll
        for (int r = 0; r < 4; ++r) {
          const int lm = rb2 * 16 + quad * 4 + r;         // local row 0..31
          const int col = 32 * w + cb * 16 + n;
          Ct[lm * 256 + (((col >> 2) ^ lm) << 2) + (col & 3)] = acc[2 * p + rb2][cb][r];
        }
    __syncthreads();
    if ((w >> 1) == p) {  // waves 2p, 2p+1 read their 16 rows
      const int lm = 16 * (w & 1) + n;
#pragma unroll
      for (int kb = 0; kb < 8; ++kb) {
        const int c0 = (kb * 8 + quad * 2) ^ lm;
        const int c1 = (kb * 8 + quad * 2 + 1) ^ lm;
        const float4 f0 = *(const float4*)&Ct[lm * 256 + (c0 << 2)];
        const float4 f1 = *(const float4*)&Ct[lm * 256 + (c1 << 2)];
        Across[kb] = pack8(f0, f1);
      }
    }
    __syncthreads();
  }

  if (w < 4) {
    // out = C[:, :192] @ W2  -  sum_x g_a[x] * (T0 @ Wx); weight frags from L2
    f32x4 mn[4], V[12];
#pragma unroll
    for (int i = 0; i < 4; ++i)
#pragma unroll
      for (int r = 0; r < 4; ++r) mn[i][r] = 0.f;
#pragma unroll
    for (int i = 0; i < 12; ++i)
#pragma unroll
      for (int r = 0; r < 4; ++r) V[i][r] = 0.f;

    const unsigned char* w2f = ws + W2F_OFF;
    const unsigned char* wxf = ws + WXF_OFF;
#pragma unroll
    for (int kb = 0; kb < 6; ++kb)
#pragma unroll
      for (int cb = 0; cb < 4; ++cb) {
        const bf16x8 Bf = *(const bf16x8*)(w2f + (size_t)(kb * 4 + cb) * 1024 + fragoff);
        mn[cb] = __builtin_amdgcn_mfma_f32_16x16x32_bf16(Across[kb], Bf, mn[cb], 0, 0, 0);
      }
#pragma unroll
    for (int kb = 0; kb < 2; ++kb)
#pragma unroll
      for (int cb = 0; cb < 12; ++cb) {
        const bf16x8 Bf = *(const bf16x8*)(wxf + (size_t)(kb * 12 + cb) * 1024 + fragoff);
        V[cb] = __builtin_amdgcn_mfma_f32_16x16x32_bf16(Across[6 + kb], Bf, V[cb], 0, 0, 0);
      }

#pragma unroll
    for (int r = 0; r < 4; ++r) {
      const int af = a0 + 16 * w + quad * 4 + r;   // C/D row = quad*4 + r
      const float g0 = glds[af * 3 + 0], g1 = glds[af * 3 + 1], g2 = glds[af * 3 + 2];
#pragma unroll
      for (int cb = 0; cb < 4; ++cb) {
        const float v = mn[cb][r] - g0 * V[cb][r] - g1 * V[cb + 4][r] - g2 * V[cb + 8][r];
        out[((size_t)z * NPTS + af) * 64 + cb * 16 + n] = v;
      }
    }
  }
}

extern "C" void kernel_launch(void* const* d_in, const int* in_sizes, int n_in,
                              void* d_out, int out_size, void* d_ws, size_t ws_size,
                              hipStream_t stream) {
  const float* feat = (const float*)d_in[0];  // [8,2048,64]
  const float* geom = (const float*)d_in[1];  // [8,2048,3]
  const float* Wk   = (const float*)d_in[2];  // [3,64,64]
  float* out = (float*)d_out;                 // [8,2048,64] fp32
  unsigned char* ws = (unsigned char*)d_ws;   // ~8.44 MB used

  k1_prep<<<dim3(514), 256, 0, stream>>>(feat, geom, Wk, ws);
  k2_fused<<<dim3(256), 512, 0, stream>>>(geom, ws, out);
}